// Round 3
// baseline (229.266 us; speedup 1.0000x reference)
//
#include <hip/hip_runtime.h>
#include <hip/hip_bf16.h>

#define NN 50000
#define NE 500000
#define HD 128
#define CAP 128
#define PREP_B 24
#define ZCUR_B ((NN + 255) / 256)          // 196
#define ZAGGR_B 6250
#define FILLB_B ((NE + 255) / 256)         // 1954
#define XCONV_B 3125
#define K2_B (FILLB_B + XCONV_B)           // 5079

typedef __bf16 bf16;
typedef __attribute__((ext_vector_type(8))) __bf16 bf16x8;
typedef __attribute__((ext_vector_type(4))) float floatx4;

__device__ inline float u2f(unsigned int lo16) {
    union { unsigned int i; float f; } c; c.i = lo16 << 16; return c.f;
}

__device__ inline bf16x8 cvt8(floatx4 a, floatx4 b) {
    bf16x8 r;
#pragma unroll
    for (int j = 0; j < 4; j++) { r[j] = (bf16)a[j]; r[j + 4] = (bf16)b[j]; }
    return r;
}

__device__ inline void split8(const floatx4 f0, const floatx4 f1, bf16x8& hi, bf16x8& lo) {
#pragma unroll
    for (int j = 0; j < 4; j++) {
        float a = f0[j]; bf16 h = (bf16)a; hi[j] = h; lo[j] = (bf16)(a - (float)h);
        float b = f1[j]; bf16 g = (bf16)b; hi[j + 4] = g; lo[j + 4] = (bf16)(b - (float)g);
    }
}

__device__ inline bf16x8 zero8() {
    bf16x8 v;
#pragma unroll
    for (int j = 0; j < 8; j++) v[j] = (bf16)0.f;
    return v;
}

// accumulate 8 bf16 (one uint4) into two floatx4 (feats 0..3 -> f0, 4..7 -> f1)
__device__ inline void addrow(floatx4& f0, floatx4& f1, const uint4 v) {
    f0[0] += u2f(v.x & 0xffff); f0[1] += u2f(v.x >> 16);
    f0[2] += u2f(v.y & 0xffff); f0[3] += u2f(v.y >> 16);
    f1[0] += u2f(v.z & 0xffff); f1[1] += u2f(v.z >> 16);
    f1[2] += u2f(v.w & 0xffff); f1[3] += u2f(v.w >> 16);
}

// ===== K1: weights->bf16 (24) | zero cur + ovf_cnt (196) | [tier0 only: zero aggr (6250)] =====
__global__ __launch_bounds__(256) void k_setup1(
    const float* __restrict__ wl, const float* __restrict__ w0, const float* __restrict__ w1,
    const float* __restrict__ bl, const float* __restrict__ b0, const float* __restrict__ b1,
    const float* __restrict__ ow, const float* __restrict__ ob,
    bf16* __restrict__ wlb, bf16* __restrict__ w01b, bf16* __restrict__ owb,
    float* __restrict__ bias1, float* __restrict__ bias2,
    float* __restrict__ aggr, int* __restrict__ cur, int* __restrict__ ovf_cnt, int tier)
{
    const int b = blockIdx.x, tid = threadIdx.x;
    if (b < PREP_B) {
        int g = b * 256 + tid;
        int m = g >> 11, off = (g & 2047) << 3;
        if (m == 0) {
            const floatx4 a = *(const floatx4*)(wl + off);
            const floatx4 c = *(const floatx4*)(wl + off + 4);
            *(bf16x8*)(wlb + off) = cvt8(a, c);
        } else if (m == 1) {
            floatx4 a = *(const floatx4*)(w0 + off);
            floatx4 c = *(const floatx4*)(w0 + off + 4);
            const floatx4 d = *(const floatx4*)(w1 + off);
            const floatx4 e = *(const floatx4*)(w1 + off + 4);
#pragma unroll
            for (int j = 0; j < 4; j++) { a[j] += d[j]; c[j] += e[j]; }
            *(bf16x8*)(w01b + off) = cvt8(a, c);
        } else {
            const floatx4 a = *(const floatx4*)(ow + off);
            const floatx4 c = *(const floatx4*)(ow + off + 4);
            *(bf16x8*)(owb + off) = cvt8(a, c);
        }
        if (g < 128) bias1[g] = bl[g] + b0[g] + b1[g];
        else if (g < 256) bias2[g - 128] = ob[g - 128];
    } else if (b < PREP_B + ZCUR_B) {
        if (tier >= 1) {
            int i = (b - PREP_B) * 256 + tid;
            if (i < NN) cur[i] = 0;
            if (b == PREP_B && tid == 0) *ovf_cnt = 0;
        }
    } else {
        // only present in tier-0 grid: zero aggr for the atomic-scatter fallback
        int i = (b - PREP_B - ZCUR_B) * 256 + tid;
        floatx4 z = {0.f, 0.f, 0.f, 0.f};
        ((floatx4*)aggr)[i] = z;
    }
}

// ===== K2: bucket append (1954) | x->bf16 (3125) — independent, co-scheduled =====
__global__ __launch_bounds__(256) void k_setup2(
    const int* __restrict__ edge, const float* __restrict__ x,
    int* __restrict__ cur, int* __restrict__ bucket,
    int* __restrict__ ovf_cnt, int* __restrict__ ovf,
    bf16* __restrict__ xb)
{
    const int b = blockIdx.x, tid = threadIdx.x;
    if (b < FILLB_B) {
        int e = b * 256 + tid;
        if (e >= NE) return;
        int dst = edge[e];
        int src = edge[NE + e];
        int pos = atomicAdd(&cur[dst], 1);
        if (pos < CAP) {
            bucket[dst * CAP + pos] = src;
        } else {   // statistically never — correctness valve via overflow list
            int oi = atomicAdd(ovf_cnt, 1);
            ovf[2 * oi] = dst;
            ovf[2 * oi + 1] = src;
        }
    } else {
        int off = ((b - FILLB_B) * 256 + tid) << 3;
        const floatx4 a = *(const floatx4*)(x + off);
        const floatx4 c = *(const floatx4*)(x + off + 4);
        *(bf16x8*)(xb + off) = cvt8(a, c);
    }
}

// ======== fallback atomic scatter (tier-0, proven; aggr pre-zeroed by K1) ========
__global__ __launch_bounds__(256) void k_scatter(const float* __restrict__ x,
                                                 const int* __restrict__ edge,
                                                 float* __restrict__ aggr) {
    int tid = blockIdx.x * 256 + threadIdx.x;
    int e = tid >> 5;
    int c = (tid & 31) << 2;
    int dst = edge[e];
    int src = edge[NE + e];
    const floatx4 v = *(const floatx4*)(x + src * HD + c);
    float* ap = aggr + dst * HD + c;
    unsafeAtomicAdd(ap + 0, v[0]);
    unsafeAtomicAdd(ap + 1, v[1]);
    unsafeAtomicAdd(ap + 2, v[2]);
    unsafeAtomicAdd(ap + 3, v[3]);
}

// ======== fused gather-aggregate + GEMM1 + GEMM2 ========
// Weights read directly from global (L2-resident: 96 KB shared by all blocks).
// Only LDS use: per-wave transpose buffer tp (16x132 f32/wave, 33 KB) -> 4 blocks/CU by LDS.
// ZERO __syncthreads (tp regions are wave-private).
// NOTE: default launch_bounds — forcing min-waves=4 in R2 squeezed VGPR to 64 and
// collapsed gather MLP (dur 60.5 -> 79.7 us). ~88-100 VGPR keeps 4 waves/SIMD anyway.
__global__ __launch_bounds__(256) void k_fused(
    const float* __restrict__ aggr, const float* __restrict__ x, const bf16* __restrict__ xb,
    int tier,
    const int* __restrict__ cur, const int* __restrict__ bucket,
    const int* __restrict__ ovf_cnt, const int* __restrict__ ovf,
    const bf16* __restrict__ wlb, const bf16* __restrict__ w01b, const bf16* __restrict__ owb,
    const float* __restrict__ bias1, const float* __restrict__ bias2,
    float* __restrict__ out)
{
    __shared__ float tp[4 * 16 * 132];    // 33792 B; [wave][16][132], wave-private
    const int tid  = threadIdx.x;
    const int lane = tid & 63;
    const int wv   = tid >> 6;
    const int ln   = lane & 15;
    const int quad = lane >> 4;
    const int row0 = blockIdx.x * 64 + wv * 16;
    const int arow = row0 + ln;
    const bool aok = arow < NN;
    const int q8   = quad * 8;
    float* mytp = tp + wv * 2112;

    floatx4 ag0[4] = {};   // ag0[kc] = aggregated feats kc*32+q8 .. +3
    floatx4 ag1[4] = {};   // ag1[kc] = aggregated feats kc*32+q8+4 .. +7

    if (tier) {
        int deg = 0, n = 0;
        if (aok) { deg = cur[arow]; n = (deg < CAP) ? deg : CAP; }
        const int* bk = bucket + (size_t)arow * CAP;
        int t = 0;
        for (; t + 1 < n; t += 2) {       // 8 outstanding 16B gathers per lane
            const int2 s = *(const int2*)(bk + t);     // bucket rows are 8B-aligned, t even
            const bf16* r0 = xb + (size_t)s.x * HD + q8;
            const bf16* r1 = xb + (size_t)s.y * HD + q8;
            const uint4 a0 = *(const uint4*)(r0);
            const uint4 a1 = *(const uint4*)(r0 + 32);
            const uint4 a2 = *(const uint4*)(r0 + 64);
            const uint4 a3 = *(const uint4*)(r0 + 96);
            const uint4 c0 = *(const uint4*)(r1);
            const uint4 c1 = *(const uint4*)(r1 + 32);
            const uint4 c2 = *(const uint4*)(r1 + 64);
            const uint4 c3 = *(const uint4*)(r1 + 96);
            addrow(ag0[0], ag1[0], a0); addrow(ag0[1], ag1[1], a1);
            addrow(ag0[2], ag1[2], a2); addrow(ag0[3], ag1[3], a3);
            addrow(ag0[0], ag1[0], c0); addrow(ag0[1], ag1[1], c1);
            addrow(ag0[2], ag1[2], c2); addrow(ag0[3], ag1[3], c3);
        }
        if (t < n) {
            const int s0 = bk[t];
            const bf16* r0 = xb + (size_t)s0 * HD + q8;
            const uint4 a0 = *(const uint4*)(r0);
            const uint4 a1 = *(const uint4*)(r0 + 32);
            const uint4 a2 = *(const uint4*)(r0 + 64);
            const uint4 a3 = *(const uint4*)(r0 + 96);
            addrow(ag0[0], ag1[0], a0); addrow(ag0[1], ag1[1], a1);
            addrow(ag0[2], ag1[2], a2); addrow(ag0[3], ag1[3], a3);
        }
        if (deg > CAP) {                  // never fires for the bench inputs
            const int m = *ovf_cnt;
            for (int i = 0; i < m; i++) {
                if (ovf[2 * i] == arow) {
                    const bf16* r0 = xb + (size_t)ovf[2 * i + 1] * HD + q8;
                    const uint4 a0 = *(const uint4*)(r0);
                    const uint4 a1 = *(const uint4*)(r0 + 32);
                    const uint4 a2 = *(const uint4*)(r0 + 64);
                    const uint4 a3 = *(const uint4*)(r0 + 96);
                    addrow(ag0[0], ag1[0], a0); addrow(ag0[1], ag1[1], a1);
                    addrow(ag0[2], ag1[2], a2); addrow(ag0[3], ag1[3], a3);
                }
            }
        }
    } else if (aok) {                     // tier-0: aggr came from the atomic scatter
#pragma unroll
        for (int kc = 0; kc < 4; kc++) {
            ag0[kc] = *(const floatx4*)(aggr + (size_t)arow * HD + kc * 32 + q8);
            ag1[kc] = *(const floatx4*)(aggr + (size_t)arow * HD + kc * 32 + q8 + 4);
        }
    }

    floatx4 acc[8] = {};

    // ---- GEMM1: B-fragments straight from global (L2-resident weights) ----
#pragma unroll
    for (int kc = 0; kc < 4; kc++) {
        const int k0 = kc * 32 + q8;
        bf16x8 a_hi, a_lo;
        split8(ag0[kc], ag1[kc], a_hi, a_lo);
        bf16x8 a_x = zero8();
        if (aok) {
            if (tier) {
                a_x = *(const bf16x8*)(xb + (size_t)arow * HD + k0);
            } else {
                const floatx4 g0 = *(const floatx4*)(x + (size_t)arow * HD + k0);
                const floatx4 g1 = *(const floatx4*)(x + (size_t)arow * HD + k0 + 4);
                a_x = cvt8(g0, g1);
            }
        }
#pragma unroll
        for (int nc = 0; nc < 8; nc++) {
            const bf16x8 bw  = *(const bf16x8*)(wlb  + (nc * 16 + ln) * HD + k0);
            const bf16x8 bw2 = *(const bf16x8*)(w01b + (nc * 16 + ln) * HD + k0);
            acc[nc] = __builtin_amdgcn_mfma_f32_16x16x32_bf16(a_hi, bw,  acc[nc], 0, 0, 0);
            acc[nc] = __builtin_amdgcn_mfma_f32_16x16x32_bf16(a_lo, bw,  acc[nc], 0, 0, 0);
            acc[nc] = __builtin_amdgcn_mfma_f32_16x16x32_bf16(a_x,  bw2, acc[nc], 0, 0, 0);
        }
    }

    // ---- relu(h)+bias1 -> wave-private tp (transpose C-layout -> A-layout) ----
#pragma unroll
    for (int nc = 0; nc < 8; nc++) {
        const int col = nc * 16 + ln;
        const float bv = bias1[col];
#pragma unroll
        for (int r = 0; r < 4; r++) {
            float v = acc[nc][r] + bv;
            mytp[(quad * 4 + r) * 132 + col] = (v > 0.f ? v : 0.f);
        }
        acc[nc][0] = acc[nc][1] = acc[nc][2] = acc[nc][3] = 0.f;
    }
    // same-wave LDS RAW: compiler inserts the lgkmcnt wait; no barrier needed.

    // ---- GEMM2 ----
#pragma unroll
    for (int kc = 0; kc < 4; kc++) {
        const int k0 = kc * 32 + q8;
        const floatx4 f0 = *(const floatx4*)(mytp + ln * 132 + k0);
        const floatx4 f1 = *(const floatx4*)(mytp + ln * 132 + k0 + 4);
        bf16x8 a_hi, a_lo;
        split8(f0, f1, a_hi, a_lo);
#pragma unroll
        for (int nc = 0; nc < 8; nc++) {
            const bf16x8 bw = *(const bf16x8*)(owb + (nc * 16 + ln) * HD + k0);
            acc[nc] = __builtin_amdgcn_mfma_f32_16x16x32_bf16(a_hi, bw, acc[nc], 0, 0, 0);
            acc[nc] = __builtin_amdgcn_mfma_f32_16x16x32_bf16(a_lo, bw, acc[nc], 0, 0, 0);
        }
    }

#pragma unroll
    for (int nc = 0; nc < 8; nc++) {
        const int col = nc * 16 + ln;
        const float bv = bias2[col];
#pragma unroll
        for (int r = 0; r < 4; r++) {
            const int row = row0 + quad * 4 + r;
            if (row < NN) out[row * 128 + col] = acc[nc][r] + bv;
        }
    }
}

extern "C" void kernel_launch(void* const* d_in, const int* in_sizes, int n_in,
                              void* d_out, int out_size, void* d_ws, size_t ws_size,
                              hipStream_t stream) {
    const float* x_a     = (const float*)d_in[0];
    const int*   edge_ba = (const int*)d_in[3];
    const float* c1_w0_w = (const float*)d_in[10];
    const float* c1_w0_b = (const float*)d_in[11];
    const float* c1_wl_w = (const float*)d_in[12];
    const float* c1_wl_b = (const float*)d_in[13];
    const float* c1_w1_w = (const float*)d_in[14];
    const float* c1_w1_b = (const float*)d_in[15];
    const float* out_w   = (const float*)d_in[16];
    const float* out_b   = (const float*)d_in[17];

    char* p = (char*)d_ws;
    float* aggr  = (float*)p;   p += (size_t)NN * HD * 4;     // 25.6 MB (tier-0 fallback only)
    bf16*  wlb   = (bf16*)p;    p += 32768;
    bf16*  w01b  = (bf16*)p;    p += 32768;
    bf16*  owb   = (bf16*)p;    p += 32768;
    float* bias1 = (float*)p;   p += 512;
    float* bias2 = (float*)p;   p += 512;
    const size_t WS_FALL = (size_t)(p - (char*)d_ws);         // ~25.7 MB
    int*   cur    = (int*)p;    p += 200704;                  // NN ints (padded)
    int*   bucket = (int*)p;    p += (size_t)NN * CAP * 4;    // 25.6 MB
    bf16*  xb     = (bf16*)p;   p += (size_t)NN * HD * 2;     // 12.8 MB
    int*   ovf_cnt= (int*)p;    p += 256;
    int*   ovf    = (int*)p;    p += (size_t)NE * 2 * 4;      // 4 MB overflow (dst,src) pairs
    const size_t WS_BUCKET = (size_t)(p - (char*)d_ws);       // ~68.5 MB (ws = 256 MiB)
    (void)WS_FALL;

    const int tier = (ws_size >= WS_BUCKET) ? 1 : 0;

    const int k1_grid = tier ? (PREP_B + ZCUR_B) : (PREP_B + ZCUR_B + ZAGGR_B);
    k_setup1<<<k1_grid, 256, 0, stream>>>(c1_wl_w, c1_w0_w, c1_w1_w,
                                          c1_wl_b, c1_w0_b, c1_w1_b,
                                          out_w, out_b,
                                          wlb, w01b, owb, bias1, bias2,
                                          aggr, cur, ovf_cnt, tier);

    if (tier) {
        k_setup2<<<K2_B, 256, 0, stream>>>(edge_ba, x_a, cur, bucket, ovf_cnt, ovf, xb);
    } else {
        k_scatter<<<NE * 32 / 256, 256, 0, stream>>>(x_a, edge_ba, aggr);
    }

    k_fused<<<(NN + 63) / 64, 256, 0, stream>>>(aggr, x_a, xb, tier,
                                                cur, bucket, ovf_cnt, ovf,
                                                wlb, w01b, owb, bias1, bias2,
                                                (float*)d_out);
}

// Round 4
// 189.394 us; speedup vs baseline: 1.2105x; 1.2105x over previous
//
#include <hip/hip_runtime.h>
#include <hip/hip_bf16.h>

#define NN 50000
#define NE 500000
#define HD 128
#define CAP 128
#define PREP_B 24
#define ZCUR_B ((NN + 255) / 256)          // 196
#define ZAGGR_B 6250
#define FILLB_B ((NE + 255) / 256)         // 1954
#define XCONV_B 3125
#define K2_B (FILLB_B + XCONV_B)           // 5079

typedef __bf16 bf16;
typedef __attribute__((ext_vector_type(8))) __bf16 bf16x8;
typedef __attribute__((ext_vector_type(4))) float floatx4;

__device__ inline float u2f(unsigned int lo16) {
    union { unsigned int i; float f; } c; c.i = lo16 << 16; return c.f;
}

__device__ inline bf16x8 cvt8(floatx4 a, floatx4 b) {
    bf16x8 r;
#pragma unroll
    for (int j = 0; j < 4; j++) { r[j] = (bf16)a[j]; r[j + 4] = (bf16)b[j]; }
    return r;
}

__device__ inline void split8(const floatx4 f0, const floatx4 f1, bf16x8& hi, bf16x8& lo) {
#pragma unroll
    for (int j = 0; j < 4; j++) {
        float a = f0[j]; bf16 h = (bf16)a; hi[j] = h; lo[j] = (bf16)(a - (float)h);
        float b = f1[j]; bf16 g = (bf16)b; hi[j + 4] = g; lo[j + 4] = (bf16)(b - (float)g);
    }
}

__device__ inline bf16x8 zero8() {
    bf16x8 v;
#pragma unroll
    for (int j = 0; j < 8; j++) v[j] = (bf16)0.f;
    return v;
}

// accumulate 8 bf16 (one uint4) into two floatx4 (feats 0..3 -> f0, 4..7 -> f1)
__device__ inline void addrow(floatx4& f0, floatx4& f1, const uint4 v) {
    f0[0] += u2f(v.x & 0xffff); f0[1] += u2f(v.x >> 16);
    f0[2] += u2f(v.y & 0xffff); f0[3] += u2f(v.y >> 16);
    f1[0] += u2f(v.z & 0xffff); f1[1] += u2f(v.z >> 16);
    f1[2] += u2f(v.w & 0xffff); f1[3] += u2f(v.w >> 16);
}

// ===== K1: weights->bf16 (24) | zero cur + ovf_cnt (196) | [tier0 only: zero aggr (6250)] =====
__global__ __launch_bounds__(256) void k_setup1(
    const float* __restrict__ wl, const float* __restrict__ w0, const float* __restrict__ w1,
    const float* __restrict__ bl, const float* __restrict__ b0, const float* __restrict__ b1,
    const float* __restrict__ ow, const float* __restrict__ ob,
    bf16* __restrict__ wlb, bf16* __restrict__ w01b, bf16* __restrict__ owb,
    float* __restrict__ bias1, float* __restrict__ bias2,
    float* __restrict__ aggr, int* __restrict__ cur, int* __restrict__ ovf_cnt, int tier)
{
    const int b = blockIdx.x, tid = threadIdx.x;
    if (b < PREP_B) {
        int g = b * 256 + tid;
        int m = g >> 11, off = (g & 2047) << 3;
        if (m == 0) {
            const floatx4 a = *(const floatx4*)(wl + off);
            const floatx4 c = *(const floatx4*)(wl + off + 4);
            *(bf16x8*)(wlb + off) = cvt8(a, c);
        } else if (m == 1) {
            floatx4 a = *(const floatx4*)(w0 + off);
            floatx4 c = *(const floatx4*)(w0 + off + 4);
            const floatx4 d = *(const floatx4*)(w1 + off);
            const floatx4 e = *(const floatx4*)(w1 + off + 4);
#pragma unroll
            for (int j = 0; j < 4; j++) { a[j] += d[j]; c[j] += e[j]; }
            *(bf16x8*)(w01b + off) = cvt8(a, c);
        } else {
            const floatx4 a = *(const floatx4*)(ow + off);
            const floatx4 c = *(const floatx4*)(ow + off + 4);
            *(bf16x8*)(owb + off) = cvt8(a, c);
        }
        if (g < 128) bias1[g] = bl[g] + b0[g] + b1[g];
        else if (g < 256) bias2[g - 128] = ob[g - 128];
    } else if (b < PREP_B + ZCUR_B) {
        if (tier >= 1) {
            int i = (b - PREP_B) * 256 + tid;
            if (i < NN) cur[i] = 0;
            if (b == PREP_B && tid == 0) *ovf_cnt = 0;
        }
    } else {
        // only present in tier-0 grid: zero aggr for the atomic-scatter fallback
        int i = (b - PREP_B - ZCUR_B) * 256 + tid;
        floatx4 z = {0.f, 0.f, 0.f, 0.f};
        ((floatx4*)aggr)[i] = z;
    }
}

// ===== K2: bucket append (1954) | x->bf16 (3125) — independent, co-scheduled =====
__global__ __launch_bounds__(256) void k_setup2(
    const int* __restrict__ edge, const float* __restrict__ x,
    int* __restrict__ cur, int* __restrict__ bucket,
    int* __restrict__ ovf_cnt, int* __restrict__ ovf,
    bf16* __restrict__ xb)
{
    const int b = blockIdx.x, tid = threadIdx.x;
    if (b < FILLB_B) {
        int e = b * 256 + tid;
        if (e >= NE) return;
        int dst = edge[e];
        int src = edge[NE + e];
        int pos = atomicAdd(&cur[dst], 1);
        if (pos < CAP) {
            bucket[dst * CAP + pos] = src;
        } else {   // statistically never — correctness valve via overflow list
            int oi = atomicAdd(ovf_cnt, 1);
            ovf[2 * oi] = dst;
            ovf[2 * oi + 1] = src;
        }
    } else {
        int off = ((b - FILLB_B) * 256 + tid) << 3;
        const floatx4 a = *(const floatx4*)(x + off);
        const floatx4 c = *(const floatx4*)(x + off + 4);
        *(bf16x8*)(xb + off) = cvt8(a, c);
    }
}

// ======== fallback atomic scatter (tier-0, proven; aggr pre-zeroed by K1) ========
__global__ __launch_bounds__(256) void k_scatter(const float* __restrict__ x,
                                                 const int* __restrict__ edge,
                                                 float* __restrict__ aggr) {
    int tid = blockIdx.x * 256 + threadIdx.x;
    int e = tid >> 5;
    int c = (tid & 31) << 2;
    int dst = edge[e];
    int src = edge[NE + e];
    const floatx4 v = *(const floatx4*)(x + src * HD + c);
    float* ap = aggr + dst * HD + c;
    unsafeAtomicAdd(ap + 0, v[0]);
    unsafeAtomicAdd(ap + 1, v[1]);
    unsafeAtomicAdd(ap + 2, v[2]);
    unsafeAtomicAdd(ap + 3, v[3]);
}

// ======== fused gather-aggregate + GEMM1 + GEMM2 with LDS overlay (~70.7 KB -> 2 blocks/CU) ====
// R1 structure (LDS-staged weights — proven fastest; global-weight variants lost 20-27 us on
// MFMA-loop serialization). LDS caps us at 2 blocks/CU regardless, so VGPRs are free up to 256:
// gather is unrolled to 4 sources / 16 outstanding uint4 loads per lane + int4 index prefetch.
__global__ __launch_bounds__(256) void k_fused(
    const float* __restrict__ aggr, const float* __restrict__ x, const bf16* __restrict__ xb,
    int tier,
    const int* __restrict__ cur, const int* __restrict__ bucket,
    const int* __restrict__ ovf_cnt, const int* __restrict__ ovf,
    const bf16* __restrict__ wlb, const bf16* __restrict__ w01b, const bf16* __restrict__ owb,
    const float* __restrict__ bias1, const float* __restrict__ bias2,
    float* __restrict__ out)
{
    __shared__ bf16 sA[128 * 136];        // wl, then ow
    __shared__ bf16 sB[128 * 136];        // w01, then tp (h transpose)
    __shared__ float b1_s[128], b2_s[128];
    float* tp = (float*)sB;               // [4][16][132]
    const int tid = threadIdx.x;

#pragma unroll
    for (int it = 0; it < 8; it++) {
        int i = tid + it * 256;
        int r = i >> 4;
        int o = (i & 15) << 3;
        *(bf16x8*)(sA + r * 136 + o) = *(const bf16x8*)(wlb  + r * 128 + o);
        *(bf16x8*)(sB + r * 136 + o) = *(const bf16x8*)(w01b + r * 128 + o);
    }
    if (tid < 128) { b1_s[tid] = bias1[tid]; b2_s[tid] = bias2[tid]; }
    // staging sync deferred to after the register gather (gather touches no LDS),
    // so staging stores drain while the gather runs.

    const int lane = tid & 63;
    const int wv   = tid >> 6;
    const int ln   = lane & 15;
    const int quad = lane >> 4;
    const int row0 = blockIdx.x * 64 + wv * 16;
    const int arow = row0 + ln;
    const bool aok = arow < NN;
    const int q8   = quad * 8;

    floatx4 ag0[4] = {};   // ag0[kc] = aggregated feats kc*32+q8 .. +3
    floatx4 ag1[4] = {};   // ag1[kc] = aggregated feats kc*32+q8+4 .. +7

    if (tier) {
        int deg = 0, n = 0;
        if (aok) { deg = cur[arow]; n = (deg < CAP) ? deg : CAP; }
        const int* bk = bucket + (size_t)arow * CAP;
        int t = 0;
        if (t + 3 < n) {
            int4 s = *(const int4*)(bk);               // bucket rows 512B-aligned
            while (t + 7 < n) {
                const int4 sn = *(const int4*)(bk + t + 4);   // prefetch next indices
                const uint4* u0 = (const uint4*)(xb + (size_t)s.x * HD + q8);
                const uint4* u1 = (const uint4*)(xb + (size_t)s.y * HD + q8);
                const uint4* u2 = (const uint4*)(xb + (size_t)s.z * HD + q8);
                const uint4* u3 = (const uint4*)(xb + (size_t)s.w * HD + q8);
                // issue all 16 loads straight-line, then unpack (max MLP)
                const uint4 v00 = u0[0], v01 = u0[4], v02 = u0[8], v03 = u0[12];
                const uint4 v10 = u1[0], v11 = u1[4], v12 = u1[8], v13 = u1[12];
                const uint4 v20 = u2[0], v21 = u2[4], v22 = u2[8], v23 = u2[12];
                const uint4 v30 = u3[0], v31 = u3[4], v32 = u3[8], v33 = u3[12];
                addrow(ag0[0], ag1[0], v00); addrow(ag0[1], ag1[1], v01);
                addrow(ag0[2], ag1[2], v02); addrow(ag0[3], ag1[3], v03);
                addrow(ag0[0], ag1[0], v10); addrow(ag0[1], ag1[1], v11);
                addrow(ag0[2], ag1[2], v12); addrow(ag0[3], ag1[3], v13);
                addrow(ag0[0], ag1[0], v20); addrow(ag0[1], ag1[1], v21);
                addrow(ag0[2], ag1[2], v22); addrow(ag0[3], ag1[3], v23);
                addrow(ag0[0], ag1[0], v30); addrow(ag0[1], ag1[1], v31);
                addrow(ag0[2], ag1[2], v32); addrow(ag0[3], ag1[3], v33);
                s = sn;
                t += 4;
            }
            {   // drain the prefetched quad
                const uint4* u0 = (const uint4*)(xb + (size_t)s.x * HD + q8);
                const uint4* u1 = (const uint4*)(xb + (size_t)s.y * HD + q8);
                const uint4* u2 = (const uint4*)(xb + (size_t)s.z * HD + q8);
                const uint4* u3 = (const uint4*)(xb + (size_t)s.w * HD + q8);
                const uint4 v00 = u0[0], v01 = u0[4], v02 = u0[8], v03 = u0[12];
                const uint4 v10 = u1[0], v11 = u1[4], v12 = u1[8], v13 = u1[12];
                const uint4 v20 = u2[0], v21 = u2[8 - 4], v22 = u2[8], v23 = u2[12];
                const uint4 v30 = u3[0], v31 = u3[4], v32 = u3[8], v33 = u3[12];
                addrow(ag0[0], ag1[0], v00); addrow(ag0[1], ag1[1], v01);
                addrow(ag0[2], ag1[2], v02); addrow(ag0[3], ag1[3], v03);
                addrow(ag0[0], ag1[0], v10); addrow(ag0[1], ag1[1], v11);
                addrow(ag0[2], ag1[2], v12); addrow(ag0[3], ag1[3], v13);
                addrow(ag0[0], ag1[0], v20); addrow(ag0[1], ag1[1], v21);
                addrow(ag0[2], ag1[2], v22); addrow(ag0[3], ag1[3], v23);
                addrow(ag0[0], ag1[0], v30); addrow(ag0[1], ag1[1], v31);
                addrow(ag0[2], ag1[2], v32); addrow(ag0[3], ag1[3], v33);
                t += 4;
            }
        }
        for (; t < n; t++) {
            const bf16* r0 = xb + (size_t)bk[t] * HD + q8;
            const uint4 a0 = *(const uint4*)(r0);
            const uint4 a1 = *(const uint4*)(r0 + 32);
            const uint4 a2 = *(const uint4*)(r0 + 64);
            const uint4 a3 = *(const uint4*)(r0 + 96);
            addrow(ag0[0], ag1[0], a0); addrow(ag0[1], ag1[1], a1);
            addrow(ag0[2], ag1[2], a2); addrow(ag0[3], ag1[3], a3);
        }
        if (deg > CAP) {                  // never fires for the bench inputs
            const int m = *ovf_cnt;
            for (int i = 0; i < m; i++) {
                if (ovf[2 * i] == arow) {
                    const bf16* r0 = xb + (size_t)ovf[2 * i + 1] * HD + q8;
                    const uint4 a0 = *(const uint4*)(r0);
                    const uint4 a1 = *(const uint4*)(r0 + 32);
                    const uint4 a2 = *(const uint4*)(r0 + 64);
                    const uint4 a3 = *(const uint4*)(r0 + 96);
                    addrow(ag0[0], ag1[0], a0); addrow(ag0[1], ag1[1], a1);
                    addrow(ag0[2], ag1[2], a2); addrow(ag0[3], ag1[3], a3);
                }
            }
        }
    } else if (aok) {                     // tier-0: aggr came from the atomic scatter
#pragma unroll
        for (int kc = 0; kc < 4; kc++) {
            ag0[kc] = *(const floatx4*)(aggr + (size_t)arow * HD + kc * 32 + q8);
            ag1[kc] = *(const floatx4*)(aggr + (size_t)arow * HD + kc * 32 + q8 + 4);
        }
    }

    __syncthreads();                      // weights staged; gather results live in regs

    floatx4 acc[8] = {};

    // ---- GEMM1 ----
#pragma unroll
    for (int kc = 0; kc < 4; kc++) {
        const int k0 = kc * 32 + q8;
        bf16x8 a_hi, a_lo;
        split8(ag0[kc], ag1[kc], a_hi, a_lo);
        bf16x8 a_x = zero8();
        if (aok) {
            if (tier) {
                a_x = *(const bf16x8*)(xb + (size_t)arow * HD + k0);
            } else {
                const floatx4 g0 = *(const floatx4*)(x + (size_t)arow * HD + k0);
                const floatx4 g1 = *(const floatx4*)(x + (size_t)arow * HD + k0 + 4);
                a_x = cvt8(g0, g1);
            }
        }
#pragma unroll
        for (int nc = 0; nc < 8; nc++) {
            const bf16x8 bw  = *(const bf16x8*)(sA + (nc * 16 + ln) * 136 + k0);
            const bf16x8 bw2 = *(const bf16x8*)(sB + (nc * 16 + ln) * 136 + k0);
            acc[nc] = __builtin_amdgcn_mfma_f32_16x16x32_bf16(a_hi, bw,  acc[nc], 0, 0, 0);
            acc[nc] = __builtin_amdgcn_mfma_f32_16x16x32_bf16(a_lo, bw,  acc[nc], 0, 0, 0);
            acc[nc] = __builtin_amdgcn_mfma_f32_16x16x32_bf16(a_x,  bw2, acc[nc], 0, 0, 0);
        }
    }
    __syncthreads();

    // ---- overlay: restage ow into sA; park relu(h) into tp (over sB) ----
#pragma unroll
    for (int it = 0; it < 8; it++) {
        int i = tid + it * 256;
        int r = i >> 4;
        int o = (i & 15) << 3;
        *(bf16x8*)(sA + r * 136 + o) = *(const bf16x8*)(owb + r * 128 + o);
    }
#pragma unroll
    for (int nc = 0; nc < 8; nc++) {
        const int col = nc * 16 + ln;
        const float bv = b1_s[col];
#pragma unroll
        for (int r = 0; r < 4; r++) {
            float v = acc[nc][r] + bv;
            tp[wv * 2112 + (quad * 4 + r) * 132 + col] = (v > 0.f ? v : 0.f);
        }
        acc[nc][0] = acc[nc][1] = acc[nc][2] = acc[nc][3] = 0.f;
    }
    __syncthreads();

    // ---- GEMM2 ----
#pragma unroll
    for (int kc = 0; kc < 4; kc++) {
        const int k0 = kc * 32 + q8;
        const floatx4 f0 = *(const floatx4*)(tp + wv * 2112 + ln * 132 + k0);
        const floatx4 f1 = *(const floatx4*)(tp + wv * 2112 + ln * 132 + k0 + 4);
        bf16x8 a_hi, a_lo;
        split8(f0, f1, a_hi, a_lo);
#pragma unroll
        for (int nc = 0; nc < 8; nc++) {
            const bf16x8 bw = *(const bf16x8*)(sA + (nc * 16 + ln) * 136 + k0);
            acc[nc] = __builtin_amdgcn_mfma_f32_16x16x32_bf16(a_hi, bw, acc[nc], 0, 0, 0);
            acc[nc] = __builtin_amdgcn_mfma_f32_16x16x32_bf16(a_lo, bw, acc[nc], 0, 0, 0);
        }
    }

#pragma unroll
    for (int nc = 0; nc < 8; nc++) {
        const int col = nc * 16 + ln;
        const float bv = b2_s[col];
#pragma unroll
        for (int r = 0; r < 4; r++) {
            const int row = row0 + quad * 4 + r;
            if (row < NN) out[row * 128 + col] = acc[nc][r] + bv;
        }
    }
}

extern "C" void kernel_launch(void* const* d_in, const int* in_sizes, int n_in,
                              void* d_out, int out_size, void* d_ws, size_t ws_size,
                              hipStream_t stream) {
    const float* x_a     = (const float*)d_in[0];
    const int*   edge_ba = (const int*)d_in[3];
    const float* c1_w0_w = (const float*)d_in[10];
    const float* c1_w0_b = (const float*)d_in[11];
    const float* c1_wl_w = (const float*)d_in[12];
    const float* c1_wl_b = (const float*)d_in[13];
    const float* c1_w1_w = (const float*)d_in[14];
    const float* c1_w1_b = (const float*)d_in[15];
    const float* out_w   = (const float*)d_in[16];
    const float* out_b   = (const float*)d_in[17];

    char* p = (char*)d_ws;
    float* aggr  = (float*)p;   p += (size_t)NN * HD * 4;     // 25.6 MB (tier-0 fallback only)
    bf16*  wlb   = (bf16*)p;    p += 32768;
    bf16*  w01b  = (bf16*)p;    p += 32768;
    bf16*  owb   = (bf16*)p;    p += 32768;
    float* bias1 = (float*)p;   p += 512;
    float* bias2 = (float*)p;   p += 512;
    const size_t WS_FALL = (size_t)(p - (char*)d_ws);         // ~25.7 MB
    int*   cur    = (int*)p;    p += 200704;                  // NN ints (padded)
    int*   bucket = (int*)p;    p += (size_t)NN * CAP * 4;    // 25.6 MB
    bf16*  xb     = (bf16*)p;   p += (size_t)NN * HD * 2;     // 12.8 MB
    int*   ovf_cnt= (int*)p;    p += 256;
    int*   ovf    = (int*)p;    p += (size_t)NE * 2 * 4;      // 4 MB overflow (dst,src) pairs
    const size_t WS_BUCKET = (size_t)(p - (char*)d_ws);       // ~68.5 MB (ws = 256 MiB)
    (void)WS_FALL;

    const int tier = (ws_size >= WS_BUCKET) ? 1 : 0;

    const int k1_grid = tier ? (PREP_B + ZCUR_B) : (PREP_B + ZCUR_B + ZAGGR_B);
    k_setup1<<<k1_grid, 256, 0, stream>>>(c1_wl_w, c1_w0_w, c1_w1_w,
                                          c1_wl_b, c1_w0_b, c1_w1_b,
                                          out_w, out_b,
                                          wlb, w01b, owb, bias1, bias2,
                                          aggr, cur, ovf_cnt, tier);

    if (tier) {
        k_setup2<<<K2_B, 256, 0, stream>>>(edge_ba, x_a, cur, bucket, ovf_cnt, ovf, xb);
    } else {
        k_scatter<<<NE * 32 / 256, 256, 0, stream>>>(x_a, edge_ba, aggr);
    }

    k_fused<<<(NN + 63) / 64, 256, 0, stream>>>(aggr, x_a, xb, tier,
                                                cur, bucket, ovf_cnt, ovf,
                                                wlb, w01b, owb, bias1, bias2,
                                                (float*)d_out);
}